// Round 1
// 1060.425 us; speedup vs baseline: 1.0077x; 1.0077x over previous
//
#include <hip/hip_runtime.h>
#include <math.h>

#define S 64
#define HF 128
#define WF 128
#define CCH 256
#define NBOX_TOT 128   // 4 batches * 32 boxes
#define PLANE (HF*WF)  // 16384
#define CROP_ELEMS ((size_t)NBOX_TOT * CCH * S * S)  // 134217728

// Per-box affine coefficients, replicated per thread (cheap, once per thread).
__device__ __forceinline__ void box_coeffs(const float* __restrict__ obb, int bn,
                                           float& cx, float& cy, float& wf, float& hf,
                                           float& cs, float& sn) {
    const float* o = obb + bn * 5;
    cx = o[0] * 0.125f;                       // /FEAT_DOWN
    cy = o[1] * 0.125f;
    wf = fmaxf(o[2], 1.0f) * 1.25f * 0.125f;  // *EXPAND/FEAT_DOWN
    hf = fmaxf(o[3], 1.0f) * 1.25f * 0.125f;
    float ang = o[4] * 0.017453292519943295f; // deg2rad
    cs = cosf(ang);
    sn = sinf(ang);
}

// Main kernel: grid = 128 boxes * 16 row-tiles; block = 256 threads.
// Wave-footprint remap: each 64-lane wave covers a 16x4 output patch
// (16-wide x 4-tall) instead of a 64x1 row. The bilinear sample positions
// step <= ~1 feature-px per output px, so a 64x1 row spans a ~34-62 px
// diagonal line (one cache line per lane in the TA); a 16x4 patch spans a
// ~9x10 px blob -> ~3-4x fewer 64B lines per gather instruction, and the
// four corner gathers share lines. Stores stay coalesced: each 16-lane
// group writes one aligned 64B line.
__global__ __launch_bounds__(256) void roi_crop_kernel(const float* __restrict__ feat,
                                                       const float* __restrict__ obb,
                                                       float* __restrict__ out) {
    const int blk = blockIdx.x;
    const int bn = blk >> 4;        // box index 0..127
    const int tile = blk & 15;      // 16 tiles of 4 rows each
    const int tid = threadIdx.x;
    // wave w (= tid>>6) owns columns [16w, 16w+16); lanes 0-15 -> row 0 of the
    // strip, lanes 16-31 -> row 1, etc.
    const int j = (tid & 15) | ((tid >> 6) << 4);
    const int i = tile * 4 + ((tid >> 4) & 3);
    const int b = bn >> 5;          // batch = bn / 32

    float cx, cy, wf, hf, cs, sn;
    box_coeffs(obb, bn, cx, cy, wf, hf, cs, sn);

    const float sx = wf * (2.0f / WF);
    const float sy = hf * (2.0f / HF);
    const float tx = cx * (2.0f / WF) - 1.0f;
    const float ty = cy * (2.0f / HF) - 1.0f;
    const float a11 = cs * sx, a12 = -sn * sy, a13 = tx;
    const float a21 = sn * sx, a22 = cs * sy, a23 = ty;

    const float X = 2.0f * ((float)j + 0.5f) / (float)S - 1.0f;
    const float Y = 2.0f * ((float)i + 0.5f) / (float)S - 1.0f;
    const float gx = a11 * X + a12 * Y + a13;
    const float gy = a21 * X + a22 * Y + a23;
    const float ix = ((gx + 1.0f) * (float)WF - 1.0f) * 0.5f;
    const float iy = ((gy + 1.0f) * (float)HF - 1.0f) * 0.5f;

    const float x0f = floorf(ix);
    const float y0f = floorf(iy);
    const float wx = ix - x0f;
    const float wy = iy - y0f;
    const int x0 = (int)x0f, y0 = (int)y0f;
    const int x1 = x0 + 1,  y1 = y0 + 1;

    const bool vx0 = (x0 >= 0) & (x0 < WF);
    const bool vx1 = (x1 >= 0) & (x1 < WF);
    const bool vy0 = (y0 >= 0) & (y0 < HF);
    const bool vy1 = (y1 >= 0) & (y1 < HF);

    const int x0c = min(max(x0, 0), WF - 1);
    const int x1c = min(max(x1, 0), WF - 1);
    const int y0c = min(max(y0, 0), HF - 1);
    const int y1c = min(max(y1, 0), HF - 1);

    // Fold validity into weights (matches reference clip+mask exactly).
    const float w00 = (1.0f - wx) * (1.0f - wy) * (float)(vx0 && vy0);
    const float w01 = wx * (1.0f - wy)          * (float)(vx1 && vy0);
    const float w10 = (1.0f - wx) * wy          * (float)(vx0 && vy1);
    const float w11 = wx * wy                   * (float)(vx1 && vy1);

    const int o00 = y0c * WF + x0c;
    const int o01 = y0c * WF + x1c;
    const int o10 = y1c * WF + x0c;
    const int o11 = y1c * WF + x1c;

    const float* __restrict__ p = feat + (size_t)b * CCH * PLANE;
    float* __restrict__ op = out + (size_t)bn * CCH * (S * S) + (size_t)(i * S + j);

#pragma unroll 8
    for (int c = 0; c < CCH; ++c) {
        const float* __restrict__ pc = p + (size_t)c * PLANE;
        float v = w00 * pc[o00] + w01 * pc[o01] + w10 * pc[o10] + w11 * pc[o11];
        // Output is a 537MB stream with no reuse -> nontemporal, keep feat in L2/L3.
        __builtin_nontemporal_store(v, op + (size_t)c * (S * S));
    }
}

// Tiny kernel: the 128 x 2 x 3 affine matrices.
__global__ void roi_mat_kernel(const float* __restrict__ obb, float* __restrict__ outm) {
    const int bn = threadIdx.x;
    if (bn >= NBOX_TOT) return;
    float cx, cy, wf, hf, cs, sn;
    box_coeffs(obb, bn, cx, cy, wf, hf, cs, sn);
    const float A  = cs * (wf / (float)S);
    const float Bv = -sn * (hf / (float)S);
    const float A2 = sn * (wf / (float)S);
    const float B2 = cs * (hf / (float)S);
    const float Cx = cx - 0.5f * (float)S * (A + Bv);
    const float Cy = cy - 0.5f * (float)S * (A2 + B2);
    float* m = outm + bn * 6;
    m[0] = A;  m[1] = Bv; m[2] = Cx;
    m[3] = A2; m[4] = B2; m[5] = Cy;
}

extern "C" void kernel_launch(void* const* d_in, const int* in_sizes, int n_in,
                              void* d_out, int out_size, void* d_ws, size_t ws_size,
                              hipStream_t stream) {
    const float* feat = (const float*)d_in[0];
    const float* obb  = (const float*)d_in[1];
    float* out = (float*)d_out;

    // crops: 128 boxes * 16 tiles blocks, 256 threads (one 64x4 strip, waves as 16x4 patches)
    roi_crop_kernel<<<NBOX_TOT * 16, 256, 0, stream>>>(feat, obb, out);
    // M_all appended after crops
    roi_mat_kernel<<<1, NBOX_TOT, 0, stream>>>(obb, out + CROP_ELEMS);
}

// Round 2
// 614.794 us; speedup vs baseline: 1.7381x; 1.7248x over previous
//
#include <hip/hip_runtime.h>
#include <math.h>

#define S 64
#define HF 128
#define WF 128
#define CCH 256
#define NBOX_TOT 128   // 4 batches * 32 boxes
#define PLANE (HF*WF)  // 16384
#define CROP_ELEMS ((size_t)NBOX_TOT * CCH * S * S)  // 134217728

#define CHUNK 16       // channels per block
#define RMAX 46        // max staged rows for a 32x32 output quadrant (<=46 by extent bound)
#define LDSW 68        // padded LDS row stride in floats (68%32==4, plus XOR swizzle)

// Per-box affine coefficients, replicated per thread (cheap, once per thread).
__device__ __forceinline__ void box_coeffs(const float* __restrict__ obb, int bn,
                                           float& cx, float& cy, float& wf, float& hf,
                                           float& cs, float& sn) {
    const float* o = obb + bn * 5;
    cx = o[0] * 0.125f;                       // /FEAT_DOWN
    cy = o[1] * 0.125f;
    wf = fmaxf(o[2], 1.0f) * 1.25f * 0.125f;  // *EXPAND/FEAT_DOWN
    hf = fmaxf(o[3], 1.0f) * 1.25f * 0.125f;
    float ang = o[4] * 0.017453292519943295f; // deg2rad
    cs = cosf(ang);
    sn = sinf(ang);
}

// Block = (box, output 32x32 quadrant, 16-channel chunk), 256 threads.
// Per channel: stage the quadrant's feature window into LDS with coalesced
// float4 loads (replaces TA-serialized per-lane gathers), bilinear from LDS.
// Double-buffered LDS; T14 split: issue next channel's global loads before
// compute, ds_write them after (HBM latency hides under LDS compute).
__global__ __launch_bounds__(256) void roi_crop_lds(const float* __restrict__ feat,
                                                    const float* __restrict__ obb,
                                                    float* __restrict__ out) {
    __shared__ float buf[2][RMAX * LDSW];   // 2 * 46*68*4 = 25 KB

    const int bid   = blockIdx.x;
    const int chunk = bid & 15;          // 16 channel-chunks
    const int quad  = (bid >> 4) & 3;    // 4 output quadrants
    const int bn    = bid >> 6;          // box 0..127
    const int qx = quad & 1, qy = quad >> 1;
    const int tid = threadIdx.x;
    const int b = bn >> 5;               // batch

    float cx, cy, wf, hf, cs, sn;
    box_coeffs(obb, bn, cx, cy, wf, hf, cs, sn);

    const float a11 = cs * (wf * (2.0f / WF));
    const float a12 = -sn * (hf * (2.0f / HF));
    const float a13 = cx * (2.0f / WF) - 1.0f;
    const float a21 = sn * (wf * (2.0f / WF));
    const float a22 = cs * (hf * (2.0f / HF));
    const float a23 = cy * (2.0f / HF) - 1.0f;

    const int j0 = qx * 32, i0 = qy * 32;

    // Reference-exact sample position (affine & monotone per axis, so the
    // 4 quadrant corners bound every interior sample).
    auto samp = [&](int j, int i, float& ix, float& iy) {
        const float X = 2.0f * ((float)j + 0.5f) * (1.0f / 64.0f) - 1.0f;
        const float Y = 2.0f * ((float)i + 0.5f) * (1.0f / 64.0f) - 1.0f;
        const float gx = a11 * X + a12 * Y + a13;
        const float gy = a21 * X + a22 * Y + a23;
        ix = ((gx + 1.0f) * (float)WF - 1.0f) * 0.5f;
        iy = ((gy + 1.0f) * (float)HF - 1.0f) * 0.5f;
    };

    float cix[4], ciy[4];
    samp(j0,      i0,      cix[0], ciy[0]);
    samp(j0 + 31, i0,      cix[1], ciy[1]);
    samp(j0,      i0 + 31, cix[2], ciy[2]);
    samp(j0 + 31, i0 + 31, cix[3], ciy[3]);
    const float ixmin = fminf(fminf(cix[0], cix[1]), fminf(cix[2], cix[3]));
    const float ixmax = fmaxf(fmaxf(cix[0], cix[1]), fmaxf(cix[2], cix[3]));
    const float iymin = fminf(fminf(ciy[0], ciy[1]), fminf(ciy[2], ciy[3]));
    const float iymax = fmaxf(fmaxf(ciy[0], ciy[1]), fmaxf(ciy[2], ciy[3]));

    const int xlo = (int)floorf(ixmin), xhi = (int)floorf(ixmax);
    const int ylo = (int)floorf(iymin), yhi = (int)floorf(iymax);

    // Staged window (clamped; degenerate off-map quadrants give tiny windows
    // whose samples all carry zero weight but still index in-bounds LDS).
    const int colStart = min(max(0, xlo) & ~15, 112);
    const int colEnd   = max(colStart, min(WF - 1, xhi + 1));
    const int Wneed    = colEnd - colStart + 1;          // <= 61 by extent bound
    const int rowStart = min(max(0, ylo), HF - 1);
    const int rowEnd   = max(rowStart, min(HF - 1, yhi + 1));
    const int R        = min(rowEnd - rowStart + 1, RMAX);

    // Staging geometry: lanesPerRow = W/4 (pow2), each lane loads a float4.
    int lprl;
    if (Wneed <= 16) lprl = 2; else if (Wneed <= 32) lprl = 3; else lprl = 4;
    const int rpi = 256 >> lprl;                   // rows per staging pass (64/32/16)
    const int sr  = tid >> lprl;
    const int sc4 = (tid & ((1 << lprl) - 1)) << 2;

    const int r0 = sr, r1 = sr + rpi, r2 = sr + 2 * rpi;   // <=3 passes (R<=46)
    const bool a0 = r0 < R, a1 = r1 < R, a2 = r2 < R;
    const int gc = min(colStart + sc4, WF - 4);
    // XOR-swizzled LDS slots (keeps float4 alignment; spreads banks per row)
    const int l0 = r0 * LDSW + (sc4 ^ ((r0 & 3) << 4));
    const int l1 = r1 * LDSW + (sc4 ^ ((r1 & 3) << 4));
    const int l2 = r2 * LDSW + (sc4 ^ ((r2 & 3) << 4));

    // Per-pixel channel-invariant precompute: 4 px/thread.
    // Wave = 32 cols x 2 rows -> each NT store instr covers 2 full 128B granules.
    const int jj = tid & 31;
    const int ii = tid >> 5;
    int offA[4], offB[4];
    float w00[4], w01[4], w10[4], w11[4];
#pragma unroll
    for (int s = 0; s < 4; ++s) {
        const int i = ii + 8 * s;
        float ix, iy;
        samp(j0 + jj, i0 + i, ix, iy);

        const float x0f = floorf(ix), y0f = floorf(iy);
        const float wx = ix - x0f, wy = iy - y0f;
        const int x0 = (int)x0f, y0 = (int)y0f;
        const int x1 = x0 + 1,  y1 = y0 + 1;

        const bool vx0 = (x0 >= 0) & (x0 < WF);
        const bool vx1 = (x1 >= 0) & (x1 < WF);
        const bool vy0 = (y0 >= 0) & (y0 < HF);
        const bool vy1 = (y1 >= 0) & (y1 < HF);

        const int x0c = min(max(x0, 0), WF - 1);
        const int x1c = min(max(x1, 0), WF - 1);
        const int y0c = min(max(y0, 0), HF - 1);
        const int y1c = min(max(y1, 0), HF - 1);

        w00[s] = (1.0f - wx) * (1.0f - wy) * (float)(vx0 && vy0);
        w01[s] = wx * (1.0f - wy)          * (float)(vx1 && vy0);
        w10[s] = (1.0f - wx) * wy          * (float)(vx0 && vy1);
        w11[s] = wx * wy                   * (float)(vx1 && vy1);

        const int lx0 = x0c - colStart, lx1 = x1c - colStart;
        const int ly0 = y0c - rowStart, ly1 = y1c - rowStart;
        const int sw0 = (ly0 & 3) << 4, sw1 = (ly1 & 3) << 4;
        const int o00 = ly0 * LDSW + (lx0 ^ sw0);
        const int o01 = ly0 * LDSW + (lx1 ^ sw0);
        const int o10 = ly1 * LDSW + (lx0 ^ sw1);
        const int o11 = ly1 * LDSW + (lx1 ^ sw1);
        offA[s] = (o00 << 16) | o01;   // all offsets < 46*68+64 < 65536
        offB[s] = (o10 << 16) | o11;
    }

    const float* fbase = feat + ((size_t)b * CCH + (size_t)chunk * CHUNK) * PLANE
                              + (size_t)rowStart * WF;
    float* obase = out + ((size_t)bn * CCH + (size_t)chunk * CHUNK) * (S * S)
                       + (size_t)((i0 + ii) * S + j0 + jj);

    float4 s0v, s1v, s2v;
    auto stage_load = [&](int ch) {
        const float* p = fbase + (size_t)ch * PLANE;
        if (a0) s0v = *(const float4*)(p + r0 * WF + gc);
        if (a1) s1v = *(const float4*)(p + r1 * WF + gc);
        if (a2) s2v = *(const float4*)(p + r2 * WF + gc);
    };
    auto stage_write = [&](float* bp) {
        if (a0) *(float4*)(bp + l0) = s0v;
        if (a1) *(float4*)(bp + l1) = s1v;
        if (a2) *(float4*)(bp + l2) = s2v;
    };

    stage_load(0);
    stage_write(buf[0]);

    for (int cc = 0; cc < CHUNK; ++cc) {
        __syncthreads();                       // buf[cc&1] staged; buf[(cc+1)&1] free
        const bool more = (cc + 1) < CHUNK;
        if (more) stage_load(cc + 1);          // issue early: latency hides under compute

        const float* bp = buf[cc & 1];
        float* op = obase + (size_t)cc * (S * S);
#pragma unroll
        for (int s = 0; s < 4; ++s) {
            const int oA = offA[s], oB = offB[s];
            const float f00 = bp[oA >> 16];
            const float f01 = bp[oA & 0xffff];
            const float f10 = bp[oB >> 16];
            const float f11 = bp[oB & 0xffff];
            const float v = w00[s] * f00 + w01[s] * f01 + w10[s] * f10 + w11[s] * f11;
            __builtin_nontemporal_store(v, op + s * (8 * S));
        }

        if (more) stage_write(buf[(cc + 1) & 1]);  // vmcnt inserted by compiler
    }
}

// Tiny kernel: the 128 x 2 x 3 affine matrices.
__global__ void roi_mat_kernel(const float* __restrict__ obb, float* __restrict__ outm) {
    const int bn = threadIdx.x;
    if (bn >= NBOX_TOT) return;
    float cx, cy, wf, hf, cs, sn;
    box_coeffs(obb, bn, cx, cy, wf, hf, cs, sn);
    const float A  = cs * (wf / (float)S);
    const float Bv = -sn * (hf / (float)S);
    const float A2 = sn * (wf / (float)S);
    const float B2 = cs * (hf / (float)S);
    const float Cx = cx - 0.5f * (float)S * (A + Bv);
    const float Cy = cy - 0.5f * (float)S * (A2 + B2);
    float* m = outm + bn * 6;
    m[0] = A;  m[1] = Bv; m[2] = Cx;
    m[3] = A2; m[4] = B2; m[5] = Cy;
}

extern "C" void kernel_launch(void* const* d_in, const int* in_sizes, int n_in,
                              void* d_out, int out_size, void* d_ws, size_t ws_size,
                              hipStream_t stream) {
    const float* feat = (const float*)d_in[0];
    const float* obb  = (const float*)d_in[1];
    float* out = (float*)d_out;

    // crops: 128 boxes * 4 quadrants * 16 channel-chunks
    roi_crop_lds<<<NBOX_TOT * 4 * 16, 256, 0, stream>>>(feat, obb, out);
    // M_all appended after crops
    roi_mat_kernel<<<1, NBOX_TOT, 0, stream>>>(obb, out + CROP_ELEMS);
}